// Round 1
// baseline (21.764 us; speedup 1.0000x reference)
//
#include <hip/hip_runtime.h>
#include <math.h>

// Problem constants (match reference)
#define NDT   9
#define NT    2160      // forcing steps == NFORCING
#define NSUB  60
#define FC_D  1e-4
#define DT_D  60.0

#define SCAN_T 256
#define CHUNK  9        // ceil(2160/256)

// ---------------------------------------------------------------------------
// K1: per forcing step t: Kt row (Gaussian-basis matvec, row-normalized),
//     Ekman current Ce = Kt0*T/(Kt1 + i*FC). Store Kt1, Ue=Re(Ce), Ve=Im(Ce).
// ---------------------------------------------------------------------------
__global__ __launch_bounds__(256) void prep_kernel(
    const float* __restrict__ pk,
    const float* __restrict__ TAx,
    const float* __restrict__ TAy,
    float* __restrict__ Kt1,
    float* __restrict__ Ue,
    float* __restrict__ Ve) {
  int t = blockIdx.x * blockDim.x + threadIdx.x;
  if (t >= NT) return;
  double gt = (double)t * 3600.0;
  double S = 0.0, a0 = 0.0, a1 = 0.0;
#pragma unroll
  for (int j = 0; j < NDT; ++j) {
    double d = (gt - (double)j * 864000.0) * (1.0 / 864000.0);
    double w = exp(-0.5 * d * d);
    S  += w;
    a0 += w * exp((double)pk[2 * j]);
    a1 += w * exp((double)pk[2 * j + 1]);
  }
  double k0 = a0 / S, k1 = a1 / S;
  double tax = (double)TAx[t], tay = (double)TAy[t];
  double den = k1 * k1 + FC_D * FC_D;
  double s = k0 / den;
  Kt1[t] = (float)k1;
  // Ce = k0*(tax + i*tay)*(k1 - i*FC)/den
  Ue[t] = (float)(s * (tax * k1 + tay * FC_D));
  Ve[t] = (float)(s * (tay * k1 - tax * FC_D));
}

// ---------------------------------------------------------------------------
// K2: per hour h: compose the 60 Euler substeps into one affine map
//     W -> C*W + D  (complex). Substep: c = (1 - dt*k_interp, -dt*FC),
//     d = -dt*(dUe + i*dVe) with the reference's interpolation/index rules.
// ---------------------------------------------------------------------------
__device__ inline double grad_at(const float* __restrict__ X, int i) {
  // jnp.gradient along axis 0 with spacing DT=60 (reference quirk)
  if (i == 0)      return ((double)X[1]      - (double)X[0])      * (1.0 / 60.0);
  if (i == NT - 1) return ((double)X[NT - 1] - (double)X[NT - 2]) * (1.0 / 60.0);
  return ((double)X[i + 1] - (double)X[i - 1]) * (1.0 / 120.0);
}

__global__ __launch_bounds__(256) void hours_kernel(
    const float* __restrict__ Kt1,
    const float* __restrict__ Ue,
    const float* __restrict__ Ve,
    double* __restrict__ hc) {   // [NT][4]: Cr,Ci,Dr,Di
  int h = blockIdx.x * blockDim.x + threadIdx.x;
  if (h >= NT) return;
  int itsup = (h + 1 >= NT) ? (NT - 1) : (h + 1);   // jnp where(...,-1) wraps to NT-1
  double dUa = grad_at(Ue, h), dUb = grad_at(Ue, itsup);
  double dVa = grad_at(Ve, h), dVb = grad_at(Ve, itsup);
  double kB = (double)Kt1[itsup];

  double Cr = 1.0, Ci = 0.0, Dr = 0.0, Di = 0.0;
  const double ci = -DT_D * FC_D;  // -0.006, constant
  for (int iin = 0; iin < NSUB; ++iin) {
    int it  = h * NSUB + iin;
    int idx = it - 1;
    if (idx < 0)      idx = NT - 1;   // JAX wraps negative index
    if (idx > NT - 1) idx = NT - 1;   // JAX clamps OOB index
    double kA = (double)Kt1[idx];
    double aa = (double)iin * (1.0 / (double)NSUB);
    double om = 1.0 - aa;
    double kt  = om * kA  + aa * kB;
    double cr  = 1.0 - DT_D * kt;
    double dUe = om * dUa + aa * dUb;
    double dVe = om * dVa + aa * dVb;
    double dr = -DT_D * dUe, di = -DT_D * dVe;
    // compose substep after current: C' = c*C ; D' = c*D + d
    double nCr = cr * Cr - ci * Ci;
    double nCi = cr * Ci + ci * Cr;
    double nDr = cr * Dr - ci * Di + dr;
    double nDi = cr * Di + ci * Dr + di;
    Cr = nCr; Ci = nCi; Dr = nDr; Di = nDi;
  }
  double4 v; v.x = Cr; v.y = Ci; v.z = Dr; v.w = Di;
  reinterpret_cast<double4*>(hc)[h] = v;
}

// ---------------------------------------------------------------------------
// K3: single-block exclusive prefix scan over the 2160 hour-composites
//     (affine-map monoid), then write out[h] = Ue[h] + Re(prefixD),
//     out[NT+h] = Ve[h] + Im(prefixD). W0 = 0 so only D matters for output.
// ---------------------------------------------------------------------------
__global__ __launch_bounds__(SCAN_T) void scan_out_kernel(
    const double* __restrict__ hc,
    const float* __restrict__ Ue,
    const float* __restrict__ Ve,
    float* __restrict__ out) {
  int tid = threadIdx.x;
  int h0 = tid * CHUNK;

  // pass 1: thread-chunk total
  double Cr = 1.0, Ci = 0.0, Dr = 0.0, Di = 0.0;
  for (int m = 0; m < CHUNK; ++m) {
    int h = h0 + m;
    if (h >= NT) break;
    double4 e = reinterpret_cast<const double4*>(hc)[h];
    double nCr = e.x * Cr - e.y * Ci;
    double nCi = e.x * Ci + e.y * Cr;
    double nDr = e.x * Dr - e.y * Di + e.z;
    double nDi = e.x * Di + e.y * Dr + e.w;
    Cr = nCr; Ci = nCi; Dr = nDr; Di = nDi;
  }

  // Hillis-Steele inclusive scan over 256 chunk totals
  __shared__ double sCr[SCAN_T], sCi[SCAN_T], sDr[SCAN_T], sDi[SCAN_T];
  sCr[tid] = Cr; sCi[tid] = Ci; sDr[tid] = Dr; sDi[tid] = Di;
  __syncthreads();
  for (int s = 1; s < SCAN_T; s <<= 1) {
    double pCr = 1.0, pCi = 0.0, pDr = 0.0, pDi = 0.0;
    bool has = (tid >= s);
    if (has) { pCr = sCr[tid - s]; pCi = sCi[tid - s]; pDr = sDr[tid - s]; pDi = sDi[tid - s]; }
    __syncthreads();
    if (has) {
      // cur (later) ∘ partner (earlier): C = Ccur*Cp ; D = Ccur*Dp + Dcur
      double nCr = Cr * pCr - Ci * pCi;
      double nCi = Cr * pCi + Ci * pCr;
      double nDr = Cr * pDr - Ci * pDi + Dr;
      double nDi = Cr * pDi + Ci * pDr + Di;
      Cr = nCr; Ci = nCi; Dr = nDr; Di = nDi;
      sCr[tid] = Cr; sCi[tid] = Ci; sDr[tid] = Dr; sDi[tid] = Di;
    }
    __syncthreads();
  }

  // exclusive offset for this thread = inclusive total of thread tid-1
  double rCr = 1.0, rCi = 0.0, rDr = 0.0, rDi = 0.0;
  if (tid > 0) { rCr = sCr[tid - 1]; rCi = sCi[tid - 1]; rDr = sDr[tid - 1]; rDi = sDi[tid - 1]; }

  // pass 2: walk the chunk, writing exclusive-prefix D before composing each hour
  for (int m = 0; m < CHUNK; ++m) {
    int h = h0 + m;
    if (h >= NT) break;
    out[h]      = (float)((double)Ue[h] + rDr);
    out[NT + h] = (float)((double)Ve[h] + rDi);
    double4 e = reinterpret_cast<const double4*>(hc)[h];
    double nCr = e.x * rCr - e.y * rCi;
    double nCi = e.x * rCi + e.y * rCr;
    double nDr = e.x * rDr - e.y * rDi + e.z;
    double nDi = e.x * rDi + e.y * rDr + e.w;
    rCr = nCr; rCi = nCi; rDr = nDr; rDi = nDi;
  }
}

// ---------------------------------------------------------------------------
extern "C" void kernel_launch(void* const* d_in, const int* in_sizes, int n_in,
                              void* d_out, int out_size, void* d_ws, size_t ws_size,
                              hipStream_t stream) {
  const float* pk  = (const float*)d_in[0];
  const float* TAx = (const float*)d_in[1];
  const float* TAy = (const float*)d_in[2];
  float* out = (float*)d_out;

  char* ws = (char*)d_ws;
  float* Kt1 = (float*)ws;            // NT f32
  float* Ue  = Kt1 + NT;              // NT f32
  float* Ve  = Ue + NT;               // NT f32
  // 3*NT*4 = 25920 bytes, 32B-aligned; then NT*4 doubles for hour composites
  double* hc = (double*)(ws + 3 * NT * sizeof(float));

  int blocks = (NT + 255) / 256;
  prep_kernel<<<blocks, 256, 0, stream>>>(pk, TAx, TAy, Kt1, Ue, Ve);
  hours_kernel<<<blocks, 256, 0, stream>>>(Kt1, Ue, Ve, hc);
  scan_out_kernel<<<1, SCAN_T, 0, stream>>>(hc, Ue, Ve, out);
}